// Round 8
// baseline (784.303 us; speedup 1.0000x reference)
//
#include <hip/hip_runtime.h>
#include <hip/hip_cooperative_groups.h>
#include <stdint.h>

namespace cg = cooperative_groups;

#define N_NODES 50000
#define N_EDGES 600000
#define DIM     128
#define N_GRAPHS 512
#define NCH     196           // ceil(50000/256) chunks for rowptr scan
#define NTILE   782           // ceil(50000/64) mlp tiles

typedef __attribute__((ext_vector_type(8))) short bf16x8;
typedef __attribute__((ext_vector_type(4))) float f32x4;

__device__ __forceinline__ short f2bf(float f) {
    union { float f; uint32_t u; } c; c.f = f;
    uint32_t u = c.u;
    u += 0x7fffu + ((u >> 16) & 1u);   // round-to-nearest-even
    return (short)(u >> 16);
}
__device__ __forceinline__ float bflo(uint32_t u) {
    union { uint32_t u; float f; } c; c.u = u << 16; return c.f;
}
__device__ __forceinline__ float bfhi(uint32_t u) {
    union { uint32_t u; float f; } c; c.u = u & 0xffff0000u; return c.f;
}

#define N8_CVT (N_NODES * DIM / 8)        // 800000
#define NZ16   (N_NODES * 4 / 16)         // 12500 (cnt only)
#define NPACK  8192
#define PREP_TOTAL (N8_CVT + NZ16 + NPACK)

// ---- agg: one 16-lane group per node, 4/1-unrolled (proven round-5 body) ----
__device__ __forceinline__ void agg_phase(const ushort* __restrict__ h,
                                          const int* __restrict__ rowptr,
                                          const int* __restrict__ csr,
                                          ushort* __restrict__ agg,
                                          int gid, int gsz) {
    const uint4* h4 = (const uint4*)h;
    const int l15 = gid & 15;
    const int ngrp = gsz >> 4;
    for (int node = gid >> 4; node < N_NODES; node += ngrp) {
        uint4 v = h4[(size_t)node * 16 + l15];    // self-loop
        float a0 = bflo(v.x), a1 = bfhi(v.x), a2 = bflo(v.y), a3 = bfhi(v.y);
        float a4 = bflo(v.z), a5 = bfhi(v.z), a6 = bflo(v.w), a7 = bfhi(v.w);
        const int s = rowptr[node];
        const int e = rowptr[node + 1];
        int i = s;
        for (; i + 3 < e; i += 4) {
            int i0 = csr[i], i1 = csr[i + 1], i2 = csr[i + 2], i3 = csr[i + 3];
            uint4 v0 = h4[(size_t)i0 * 16 + l15];
            uint4 v1 = h4[(size_t)i1 * 16 + l15];
            uint4 v2 = h4[(size_t)i2 * 16 + l15];
            uint4 v3 = h4[(size_t)i3 * 16 + l15];
            a0 += bflo(v0.x); a1 += bfhi(v0.x); a2 += bflo(v0.y); a3 += bfhi(v0.y);
            a4 += bflo(v0.z); a5 += bfhi(v0.z); a6 += bflo(v0.w); a7 += bfhi(v0.w);
            a0 += bflo(v1.x); a1 += bfhi(v1.x); a2 += bflo(v1.y); a3 += bfhi(v1.y);
            a4 += bflo(v1.z); a5 += bfhi(v1.z); a6 += bflo(v1.w); a7 += bfhi(v1.w);
            a0 += bflo(v2.x); a1 += bfhi(v2.x); a2 += bflo(v2.y); a3 += bfhi(v2.y);
            a4 += bflo(v2.z); a5 += bfhi(v2.z); a6 += bflo(v2.w); a7 += bfhi(v2.w);
            a0 += bflo(v3.x); a1 += bfhi(v3.x); a2 += bflo(v3.y); a3 += bfhi(v3.y);
            a4 += bflo(v3.z); a5 += bfhi(v3.z); a6 += bflo(v3.w); a7 += bfhi(v3.w);
        }
        for (; i < e; ++i) {
            uint4 v0 = h4[(size_t)csr[i] * 16 + l15];
            a0 += bflo(v0.x); a1 += bfhi(v0.x); a2 += bflo(v0.y); a3 += bfhi(v0.y);
            a4 += bflo(v0.z); a5 += bfhi(v0.z); a6 += bflo(v0.w); a7 += bfhi(v0.w);
        }
        uint4 r;
        r.x = (uint32_t)(uint16_t)f2bf(a0) | ((uint32_t)(uint16_t)f2bf(a1) << 16);
        r.y = (uint32_t)(uint16_t)f2bf(a2) | ((uint32_t)(uint16_t)f2bf(a3) << 16);
        r.z = (uint32_t)(uint16_t)f2bf(a4) | ((uint32_t)(uint16_t)f2bf(a5) << 16);
        r.w = (uint32_t)(uint16_t)f2bf(a6) | ((uint32_t)(uint16_t)f2bf(a7) << 16);
        ((uint4*)agg)[(size_t)node * 16 + l15] = r;
    }
}

// ---- mlp: 4 waves/block, 16 nodes/wave (proven round-3 body), tile-strided ----
__device__ void mlp_phase(const ushort* __restrict__ A,
                          const short* __restrict__ W1p, const float* __restrict__ b1,
                          const short* __restrict__ W2p, const float* __restrict__ b2,
                          ushort* __restrict__ Hout,
                          short (*tbuf)[16 * 144], int bid, int gdim, int tid) {
    const int wid = tid >> 6;
    const int lane = tid & 63;
    const int l15 = lane & 15;
    const int lg = lane >> 4;
    short* tb = tbuf[wid];
    for (int tile = bid; tile < NTILE; tile += gdim) {
        const int node0 = tile * 64 + wid * 16;
        int arow = node0 + l15;
        if (arow >= N_NODES) arow = N_NODES - 1;
        const short* ap = (const short*)A + (size_t)arow * DIM + lg * 8;
        bf16x8 afr[4];
#pragma unroll
        for (int ks = 0; ks < 4; ++ks) afr[ks] = *(const bf16x8*)(ap + ks * 32);

#pragma unroll
        for (int nt = 0; nt < 8; ++nt) {
            f32x4 acc = {0.f, 0.f, 0.f, 0.f};
#pragma unroll
            for (int ks = 0; ks < 4; ++ks) {
                bf16x8 b = *(const bf16x8*)(W1p + (size_t)(((nt * 4 + ks) << 6) + lane) * 8);
                acc = __builtin_amdgcn_mfma_f32_16x16x32_bf16(afr[ks], b, acc, 0, 0, 0);
            }
            float bias = b1[nt * 16 + l15];
#pragma unroll
            for (int i = 0; i < 4; ++i) {
                int r = lg * 4 + i;
                tb[r * 144 + nt * 16 + l15] = f2bf(fmaxf(acc[i] + bias, 0.f));
            }
        }
        __syncthreads();

        bf16x8 a2[4];
#pragma unroll
        for (int ks = 0; ks < 4; ++ks)
            a2[ks] = *(const bf16x8*)(tb + l15 * 144 + ks * 32 + lg * 8);
        __syncthreads();

#pragma unroll
        for (int nt = 0; nt < 8; ++nt) {
            f32x4 acc = {0.f, 0.f, 0.f, 0.f};
#pragma unroll
            for (int ks = 0; ks < 4; ++ks) {
                bf16x8 b = *(const bf16x8*)(W2p + (size_t)(((nt * 4 + ks) << 6) + lane) * 8);
                acc = __builtin_amdgcn_mfma_f32_16x16x32_bf16(a2[ks], b, acc, 0, 0, 0);
            }
            float bias = b2[nt * 16 + l15];
#pragma unroll
            for (int i = 0; i < 4; ++i) {
                int r = lg * 4 + i;
                tb[r * 144 + nt * 16 + l15] = f2bf(acc[i] + bias);
            }
        }
        __syncthreads();

#pragma unroll
        for (int it = 0; it < 4; ++it) {
            int chunk = it * 64 + lane;
            int row = chunk >> 4;
            int seg = chunk & 15;
            bf16x8 v = *(const bf16x8*)(tb + row * 144 + seg * 8);
            int node = node0 + row;
            if (node < N_NODES) *(bf16x8*)((short*)Hout + (size_t)node * DIM + seg * 8) = v;
        }
        __syncthreads();
    }
}

__global__ __launch_bounds__(256, 4) void mega_kernel(
    const float* __restrict__ x, const int* __restrict__ ei, const int* __restrict__ xb,
    const float* __restrict__ c0W1, const float* __restrict__ c0b1,
    const float* __restrict__ c0W2, const float* __restrict__ c0b2,
    const float* __restrict__ c1W1, const float* __restrict__ c1b1,
    const float* __restrict__ c1W2, const float* __restrict__ c1b2,
    const float* __restrict__ rW1, const float* __restrict__ rb1,
    const float* __restrict__ rW2, const float* __restrict__ rb2,
    float* __restrict__ out,
    int* cnt, int* cursor, int* rowptr, int* csr,
    ushort* xbf, ushort* aggbf, ushort* hbf, short* Wp) {

    __shared__ short s_tbuf[4][16 * 144];   // 18.4 KB, aliased per phase

    cg::grid_group grid = cg::this_grid();
    const int t = threadIdx.x;
    const int bid = blockIdx.x;
    const int gdim = gridDim.x;
    const int gid = bid * 256 + t;
    const int gsz = gdim * 256;

    // ---- P0: prep (cvt x->bf16 | zero cnt | pack weights) ----
    for (int idx = gid; idx < PREP_TOTAL; idx += gsz) {
        if (idx < N8_CVT) {
            const float4* p = (const float4*)(x + (size_t)idx * 8);
            float4 lo = p[0], hi = p[1];
            bf16x8 tv;
            tv[0] = f2bf(lo.x); tv[1] = f2bf(lo.y); tv[2] = f2bf(lo.z); tv[3] = f2bf(lo.w);
            tv[4] = f2bf(hi.x); tv[5] = f2bf(hi.y); tv[6] = f2bf(hi.z); tv[7] = f2bf(hi.w);
            *(bf16x8*)(xbf + (size_t)idx * 8) = tv;
        } else {
            int z = idx - N8_CVT;
            if (z < NZ16) {
                ((uint4*)cnt)[z] = make_uint4(0, 0, 0, 0);
            } else {
                int pk = z - NZ16;
                int m = pk >> 11;
                int r = pk & 2047;
                const float* W = (m == 0) ? c0W1 : (m == 1) ? c0W2 : (m == 2) ? c1W1 : c1W2;
                int lane = r & 63;
                int ks = (r >> 6) & 3;
                int nt = r >> 8;
                int col = nt * 16 + (lane & 15);
                int k0 = ks * 32 + ((lane >> 4) << 3);
                short* dst = Wp + (size_t)pk * 8;
#pragma unroll
                for (int j = 0; j < 8; ++j) dst[j] = f2bf(W[(k0 + j) * DIM + col]);
            }
        }
    }
    grid.sync();

    // ---- P1: count ----
    for (int e = gid; e < N_EDGES; e += gsz)
        atomicAdd(&cnt[ei[N_EDGES + e]], 1);
    grid.sync();

    // ---- P2: rowptr + cursor (256-node chunks, redundant prefix base) ----
    {
        int* sc = (int*)s_tbuf;
        for (int c = bid; c < NCH; c += gdim) {
            const int lim = c << 8;
            int partial = 0;
            for (int j = t; j < lim; j += 256) partial += cnt[j];
            sc[t] = partial;
            __syncthreads();
#pragma unroll
            for (int off = 128; off; off >>= 1) {
                if (t < off) sc[t] += sc[t + off];
                __syncthreads();
            }
            const int base = sc[0];
            __syncthreads();
            int i = lim + t;
            int v = (i < N_NODES) ? cnt[i] : 0;
            sc[t] = v;
            __syncthreads();
#pragma unroll
            for (int off = 1; off < 256; off <<= 1) {
                int u = (t >= off) ? sc[t - off] : 0;
                __syncthreads();
                sc[t] += u;
                __syncthreads();
            }
            if (i < N_NODES) {
                rowptr[i + 1] = base + sc[t];
                cursor[i] = base + sc[t] - v;
            }
            if (i == 0) rowptr[0] = 0;
            __syncthreads();
        }
    }
    grid.sync();

    // ---- P3: fill csr ----
    for (int e = gid; e < N_EDGES; e += gsz) {
        int dst = ei[N_EDGES + e];
        int p = atomicAdd(&cursor[dst], 1);
        csr[p] = ei[e];
    }
    grid.sync();

    // ---- P4/P5: layer 0 ----
    agg_phase(xbf, rowptr, csr, aggbf, gid, gsz);
    grid.sync();
    mlp_phase(aggbf, Wp + 0 * 16384, c0b1, Wp + 1 * 16384, c0b2, hbf, s_tbuf, bid, gdim, t);
    grid.sync();

    // ---- P6/P7: layer 1 ----
    agg_phase(hbf, rowptr, csr, aggbf, gid, gsz);
    grid.sync();
    mlp_phase(aggbf, Wp + 2 * 16384, c1b1, Wp + 3 * 16384, c1b2, hbf, s_tbuf, bid, gdim, t);
    grid.sync();

    // ---- P8: mean-pool + regressor ----
    {
        float (*red)[128] = (float(*)[128])s_tbuf;   // 16 x 128 floats
        float* pbuf = (float*)s_tbuf + 16 * 128;     // +128 floats
        const int grp = t >> 4;    // 0..15
        const int l15 = t & 15;
        const uint4* h4 = (const uint4*)hbf;
        for (int g = bid; g < N_GRAPHS; g += gdim) {
            int lo = 0, hi = N_NODES;
            while (lo < hi) { int m = (lo + hi) >> 1; if (xb[m] < g) lo = m + 1; else hi = m; }
            int s = lo;
            hi = N_NODES;
            while (lo < hi) { int m = (lo + hi) >> 1; if (xb[m] < g + 1) lo = m + 1; else hi = m; }
            int e = lo;

            float a0=0,a1=0,a2=0,a3=0,a4=0,a5=0,a6=0,a7=0;
            for (int i = s + grp; i < e; i += 16) {
                uint4 v = h4[(size_t)i * 16 + l15];
                a0 += bflo(v.x); a1 += bfhi(v.x); a2 += bflo(v.y); a3 += bfhi(v.y);
                a4 += bflo(v.z); a5 += bfhi(v.z); a6 += bflo(v.w); a7 += bfhi(v.w);
            }
            float* rp = &red[grp][l15 * 8];
            rp[0]=a0; rp[1]=a1; rp[2]=a2; rp[3]=a3; rp[4]=a4; rp[5]=a5; rp[6]=a6; rp[7]=a7;
            __syncthreads();

            if (t < 128) {
                float acc = 0.f;
#pragma unroll
                for (int k = 0; k < 16; ++k) acc += red[k][t];
                float c = (e - s) > 0 ? (float)(e - s) : 1.0f;
                pbuf[t] = acc / c;
            }
            __syncthreads();
            if (t < 128) {
                float acc2 = rb1[t];
#pragma unroll 8
                for (int k = 0; k < DIM; ++k) acc2 = fmaf(pbuf[k], rW1[k * DIM + t], acc2);
                red[0][t] = fmaxf(acc2, 0.f) * rW2[t];
            }
            __syncthreads();
            for (int off = 64; off; off >>= 1) {
                if (t < off) red[0][t] += red[0][t + off];
                __syncthreads();
            }
            if (t == 0) out[g] = red[0][0] + rb2[0];
            __syncthreads();
        }
    }
}

extern "C" void kernel_launch(void* const* d_in, const int* in_sizes, int n_in,
                              void* d_out, int out_size, void* d_ws, size_t ws_size,
                              hipStream_t stream) {
    (void)in_sizes; (void)n_in; (void)out_size; (void)ws_size;
    const float* x     = (const float*)d_in[0];
    const int*   ei    = (const int*)d_in[1];
    const int*   xb    = (const int*)d_in[3];
    const float* c0W1  = (const float*)d_in[4];
    const float* c0b1  = (const float*)d_in[5];
    const float* c0W2  = (const float*)d_in[6];
    const float* c0b2  = (const float*)d_in[7];
    const float* c1W1  = (const float*)d_in[8];
    const float* c1b1  = (const float*)d_in[9];
    const float* c1W2  = (const float*)d_in[10];
    const float* c1b2  = (const float*)d_in[11];
    const float* rW1   = (const float*)d_in[12];
    const float* rb1   = (const float*)d_in[13];
    const float* rW2   = (const float*)d_in[14];
    const float* rb2   = (const float*)d_in[15];
    float* out = (float*)d_out;

    char* ws = (char*)d_ws;
    size_t off = 0;
    auto alloc = [&](size_t bytes) -> char* {
        char* p = ws + off;
        off = (off + bytes + 511) & ~(size_t)511;
        return p;
    };
    int*    cnt    = (int*)alloc((size_t)N_NODES * 4);
    int*    cursor = (int*)alloc((size_t)N_NODES * 4);
    int*    rowptr = (int*)alloc((size_t)(N_NODES + 1) * 4);
    int*    csr    = (int*)alloc((size_t)N_EDGES * 4);
    ushort* xbf    = (ushort*)alloc((size_t)N_NODES * DIM * 2);
    ushort* aggbf  = (ushort*)alloc((size_t)N_NODES * DIM * 2);
    ushort* hbf    = (ushort*)alloc((size_t)N_NODES * DIM * 2);
    short*  Wp     = (short*)alloc((size_t)4 * DIM * DIM * 2);

    void* args[] = { &x, &ei, &xb,
                     &c0W1, &c0b1, &c0W2, &c0b2,
                     &c1W1, &c1b1, &c1W2, &c1b2,
                     &rW1, &rb1, &rW2, &rb2,
                     &out, &cnt, &cursor, &rowptr, &csr,
                     &xbf, &aggbf, &hbf, &Wp };

    int nb = 0;
    hipOccupancyMaxActiveBlocksPerMultiprocessor(&nb, mega_kernel, 256, 0);
    if (nb < 1) nb = 1;
    int grid = nb * 256;            // 256 CUs on MI355X
    if (grid > 1024) grid = 1024;

    hipLaunchCooperativeKernel(reinterpret_cast<void*>(mega_kernel),
                               dim3(grid), dim3(256), args, 0, stream);
}

// Round 9
// 528.598 us; speedup vs baseline: 1.4837x; 1.4837x over previous
//
#include <hip/hip_runtime.h>
#include <hip/hip_cooperative_groups.h>
#include <stdint.h>

namespace cg = cooperative_groups;

#define N_NODES 50000
#define N_EDGES 600000
#define DIM     128
#define N_GRAPHS 512
#define NCH     196           // ceil(50000/256) scan chunks

typedef __attribute__((ext_vector_type(8))) short bf16x8;
typedef __attribute__((ext_vector_type(4))) float f32x4;

__device__ __forceinline__ short f2bf(float f) {
    union { float f; uint32_t u; } c; c.f = f;
    uint32_t u = c.u;
    u += 0x7fffu + ((u >> 16) & 1u);   // round-to-nearest-even
    return (short)(u >> 16);
}
__device__ __forceinline__ float bflo(uint32_t u) {
    union { uint32_t u; float f; } c; c.u = u << 16; return c.f;
}
__device__ __forceinline__ float bfhi(uint32_t u) {
    union { uint32_t u; float f; } c; c.u = u & 0xffff0000u; return c.f;
}

#define N8_CVT (N_NODES * DIM / 8)        // 800000
#define NZ16   (N_NODES * 4 / 16)         // 12500 (cnt only)
#define NPACK  8192
#define PREP_TOTAL (N8_CVT + NZ16 + NPACK)

// ---- cooperative setup: prep | count | rowptr+cursor | fill ----
// All phases low-VGPR (no MFMA, no big unrolls) -> no spill risk, high occupancy.
__global__ __launch_bounds__(256) void setup_kernel(
    const float* __restrict__ x, const int* __restrict__ ei,
    const float* __restrict__ c0W1, const float* __restrict__ c0W2,
    const float* __restrict__ c1W1, const float* __restrict__ c1W2,
    ushort* __restrict__ xbf, short* __restrict__ Wp,
    int* cnt, int* cursor, int* rowptr, int* csr) {

    __shared__ int sc[256];
    cg::grid_group grid = cg::this_grid();
    const int t = threadIdx.x;
    const int bid = blockIdx.x;
    const int gdim = gridDim.x;
    const int gid = bid * 256 + t;
    const int gsz = gdim * 256;

    // P0: cvt x->bf16 | zero cnt | pack weights
    for (int idx = gid; idx < PREP_TOTAL; idx += gsz) {
        if (idx < N8_CVT) {
            const float4* p = (const float4*)(x + (size_t)idx * 8);
            float4 lo = p[0], hi = p[1];
            bf16x8 tv;
            tv[0] = f2bf(lo.x); tv[1] = f2bf(lo.y); tv[2] = f2bf(lo.z); tv[3] = f2bf(lo.w);
            tv[4] = f2bf(hi.x); tv[5] = f2bf(hi.y); tv[6] = f2bf(hi.z); tv[7] = f2bf(hi.w);
            *(bf16x8*)(xbf + (size_t)idx * 8) = tv;
        } else {
            int z = idx - N8_CVT;
            if (z < NZ16) {
                ((uint4*)cnt)[z] = make_uint4(0, 0, 0, 0);
            } else {
                int pk = z - NZ16;
                int m = pk >> 11;
                int r = pk & 2047;
                const float* W = (m == 0) ? c0W1 : (m == 1) ? c0W2 : (m == 2) ? c1W1 : c1W2;
                int lane = r & 63;
                int ks = (r >> 6) & 3;
                int nt = r >> 8;
                int col = nt * 16 + (lane & 15);
                int k0 = ks * 32 + ((lane >> 4) << 3);
                short* dst = Wp + (size_t)pk * 8;
#pragma unroll
                for (int j = 0; j < 8; ++j) dst[j] = f2bf(W[(k0 + j) * DIM + col]);
            }
        }
    }
    grid.sync();

    // P1: count in-degrees
    for (int e = gid; e < N_EDGES; e += gsz)
        atomicAdd(&cnt[ei[N_EDGES + e]], 1);
    grid.sync();

    // P2: rowptr + cursor (256-node chunks, redundant prefix base)
    for (int c = bid; c < NCH; c += gdim) {
        const int lim = c << 8;
        int partial = 0;
        for (int j = t; j < lim; j += 256) partial += cnt[j];
        sc[t] = partial;
        __syncthreads();
#pragma unroll
        for (int off = 128; off; off >>= 1) {
            if (t < off) sc[t] += sc[t + off];
            __syncthreads();
        }
        const int base = sc[0];
        __syncthreads();
        int i = lim + t;
        int v = (i < N_NODES) ? cnt[i] : 0;
        sc[t] = v;
        __syncthreads();
#pragma unroll
        for (int off = 1; off < 256; off <<= 1) {
            int u = (t >= off) ? sc[t - off] : 0;
            __syncthreads();
            sc[t] += u;
            __syncthreads();
        }
        if (i < N_NODES) {
            rowptr[i + 1] = base + sc[t];
            cursor[i] = base + sc[t] - v;   // exclusive start = rowptr[i]
        }
        if (i == 0) rowptr[0] = 0;
        __syncthreads();
    }
    grid.sync();

    // P3: fill csr
    for (int e = gid; e < N_EDGES; e += gsz) {
        int dst = ei[N_EDGES + e];
        int p = atomicAdd(&cursor[dst], 1);
        csr[p] = ei[e];
    }
}

// one 16-lane group per node (16 lanes x 16B = full 256B row), 4 nodes/wave,
// edge loop 4/1-unrolled (proven round-5/7 config)
__global__ __launch_bounds__(256) void agg_kernel(const ushort* __restrict__ h,
                                                  const int* __restrict__ rowptr,
                                                  const int* __restrict__ csr_src,
                                                  ushort* __restrict__ agg) {
    int node = (blockIdx.x * 256 + threadIdx.x) >> 4;
    if (node >= N_NODES) return;
    int l15 = threadIdx.x & 15;
    const uint4* h4 = (const uint4*)h;

    uint4 v = h4[(size_t)node * 16 + l15];    // self-loop
    float a0 = bflo(v.x), a1 = bfhi(v.x), a2 = bflo(v.y), a3 = bfhi(v.y);
    float a4 = bflo(v.z), a5 = bfhi(v.z), a6 = bflo(v.w), a7 = bfhi(v.w);

    const int s = rowptr[node];
    const int e = rowptr[node + 1];
    int i = s;
    for (; i + 3 < e; i += 4) {
        int i0 = csr_src[i], i1 = csr_src[i + 1], i2 = csr_src[i + 2], i3 = csr_src[i + 3];
        uint4 v0 = h4[(size_t)i0 * 16 + l15];
        uint4 v1 = h4[(size_t)i1 * 16 + l15];
        uint4 v2 = h4[(size_t)i2 * 16 + l15];
        uint4 v3 = h4[(size_t)i3 * 16 + l15];
        a0 += bflo(v0.x); a1 += bfhi(v0.x); a2 += bflo(v0.y); a3 += bfhi(v0.y);
        a4 += bflo(v0.z); a5 += bfhi(v0.z); a6 += bflo(v0.w); a7 += bfhi(v0.w);
        a0 += bflo(v1.x); a1 += bfhi(v1.x); a2 += bflo(v1.y); a3 += bfhi(v1.y);
        a4 += bflo(v1.z); a5 += bfhi(v1.z); a6 += bflo(v1.w); a7 += bfhi(v1.w);
        a0 += bflo(v2.x); a1 += bfhi(v2.x); a2 += bflo(v2.y); a3 += bfhi(v2.y);
        a4 += bflo(v2.z); a5 += bfhi(v2.z); a6 += bflo(v2.w); a7 += bfhi(v2.w);
        a0 += bflo(v3.x); a1 += bfhi(v3.x); a2 += bflo(v3.y); a3 += bfhi(v3.y);
        a4 += bflo(v3.z); a5 += bfhi(v3.z); a6 += bflo(v3.w); a7 += bfhi(v3.w);
    }
    for (; i < e; ++i) {
        uint4 v0 = h4[(size_t)csr_src[i] * 16 + l15];
        a0 += bflo(v0.x); a1 += bfhi(v0.x); a2 += bflo(v0.y); a3 += bfhi(v0.y);
        a4 += bflo(v0.z); a5 += bfhi(v0.z); a6 += bflo(v0.w); a7 += bfhi(v0.w);
    }

    uint4 r;
    r.x = (uint32_t)(uint16_t)f2bf(a0) | ((uint32_t)(uint16_t)f2bf(a1) << 16);
    r.y = (uint32_t)(uint16_t)f2bf(a2) | ((uint32_t)(uint16_t)f2bf(a3) << 16);
    r.z = (uint32_t)(uint16_t)f2bf(a4) | ((uint32_t)(uint16_t)f2bf(a5) << 16);
    r.w = (uint32_t)(uint16_t)f2bf(a6) | ((uint32_t)(uint16_t)f2bf(a7) << 16);
    ((uint4*)agg)[(size_t)node * 16 + l15] = r;
}

// h_out = relu(A @ W1 + b1) @ W2 + b2 ; 32 nodes/wave, 2 waves/block (proven)
__global__ __launch_bounds__(128) void mlp_kernel(const ushort* __restrict__ A,
                                                  const short* __restrict__ W1p,
                                                  const float* __restrict__ b1,
                                                  const short* __restrict__ W2p,
                                                  const float* __restrict__ b2,
                                                  ushort* __restrict__ Hout) {
    __shared__ short tbuf[2][32 * 144];
    const int tid = threadIdx.x;
    const int wid = tid >> 6;              // 0..1
    const int lane = tid & 63;
    const int l15 = lane & 15;
    const int lg = lane >> 4;              // 0..3
    const int node0 = blockIdx.x * 64 + wid * 32;

    int rowA = node0 + l15;      if (rowA >= N_NODES) rowA = N_NODES - 1;
    int rowB = node0 + 16 + l15; if (rowB >= N_NODES) rowB = N_NODES - 1;
    const short* apA = (const short*)A + (size_t)rowA * DIM + lg * 8;
    const short* apB = (const short*)A + (size_t)rowB * DIM + lg * 8;
    bf16x8 afrA[4], afrB[4];
#pragma unroll
    for (int ks = 0; ks < 4; ++ks) {
        afrA[ks] = *(const bf16x8*)(apA + ks * 32);
        afrB[ks] = *(const bf16x8*)(apB + ks * 32);
    }

    short* tb = tbuf[wid];
#pragma unroll
    for (int nt = 0; nt < 8; ++nt) {
        f32x4 accA = {0.f, 0.f, 0.f, 0.f};
        f32x4 accB = {0.f, 0.f, 0.f, 0.f};
#pragma unroll
        for (int ks = 0; ks < 4; ++ks) {
            bf16x8 b = *(const bf16x8*)(W1p + (size_t)(((nt * 4 + ks) << 6) + lane) * 8);
            accA = __builtin_amdgcn_mfma_f32_16x16x32_bf16(afrA[ks], b, accA, 0, 0, 0);
            accB = __builtin_amdgcn_mfma_f32_16x16x32_bf16(afrB[ks], b, accB, 0, 0, 0);
        }
        float bias = b1[nt * 16 + l15];
#pragma unroll
        for (int i = 0; i < 4; ++i) {
            int r = lg * 4 + i;
            tb[r * 144 + nt * 16 + l15] = f2bf(fmaxf(accA[i] + bias, 0.f));
            tb[(r + 16) * 144 + nt * 16 + l15] = f2bf(fmaxf(accB[i] + bias, 0.f));
        }
    }
    __syncthreads();

    bf16x8 a2A[4], a2B[4];
#pragma unroll
    for (int ks = 0; ks < 4; ++ks) {
        a2A[ks] = *(const bf16x8*)(tb + l15 * 144 + ks * 32 + lg * 8);
        a2B[ks] = *(const bf16x8*)(tb + (16 + l15) * 144 + ks * 32 + lg * 8);
    }
    __syncthreads();

#pragma unroll
    for (int nt = 0; nt < 8; ++nt) {
        f32x4 accA = {0.f, 0.f, 0.f, 0.f};
        f32x4 accB = {0.f, 0.f, 0.f, 0.f};
#pragma unroll
        for (int ks = 0; ks < 4; ++ks) {
            bf16x8 b = *(const bf16x8*)(W2p + (size_t)(((nt * 4 + ks) << 6) + lane) * 8);
            accA = __builtin_amdgcn_mfma_f32_16x16x32_bf16(a2A[ks], b, accA, 0, 0, 0);
            accB = __builtin_amdgcn_mfma_f32_16x16x32_bf16(a2B[ks], b, accB, 0, 0, 0);
        }
        float bias = b2[nt * 16 + l15];
#pragma unroll
        for (int i = 0; i < 4; ++i) {
            int r = lg * 4 + i;
            tb[r * 144 + nt * 16 + l15] = f2bf(accA[i] + bias);
            tb[(r + 16) * 144 + nt * 16 + l15] = f2bf(accB[i] + bias);
        }
    }
    __syncthreads();

#pragma unroll
    for (int it = 0; it < 8; ++it) {
        int chunk = it * 64 + lane;    // 0..511
        int row = chunk >> 4;          // 0..31
        int seg = chunk & 15;
        bf16x8 v = *(const bf16x8*)(tb + row * 144 + seg * 8);
        int node = node0 + row;
        if (node < N_NODES) *(bf16x8*)((short*)Hout + (size_t)node * DIM + seg * 8) = v;
    }
}

// fused mean-pool + regressor MLP: one block (128 threads) per graph
__global__ __launch_bounds__(128) void poolreg_kernel(const ushort* __restrict__ h,
                                                      const int* __restrict__ xb,
                                                      const float* __restrict__ W1,
                                                      const float* __restrict__ b1,
                                                      const float* __restrict__ W2,
                                                      const float* __restrict__ b2,
                                                      float* __restrict__ out) {
    __shared__ float red[8][128];
    __shared__ float p[128];
    int g = blockIdx.x;
    int t = threadIdx.x;
    int grp = t >> 4;     // 0..7
    int l15 = t & 15;

    int lo = 0, hi = N_NODES;
    while (lo < hi) { int m = (lo + hi) >> 1; if (xb[m] < g) lo = m + 1; else hi = m; }
    int s = lo;
    hi = N_NODES;
    while (lo < hi) { int m = (lo + hi) >> 1; if (xb[m] < g + 1) lo = m + 1; else hi = m; }
    int e = lo;

    const uint4* h4 = (const uint4*)h;
    float a0=0,a1=0,a2=0,a3=0,a4=0,a5=0,a6=0,a7=0;
    for (int i = s + grp; i < e; i += 8) {
        uint4 v = h4[(size_t)i * 16 + l15];
        a0 += bflo(v.x); a1 += bfhi(v.x); a2 += bflo(v.y); a3 += bfhi(v.y);
        a4 += bflo(v.z); a5 += bfhi(v.z); a6 += bflo(v.w); a7 += bfhi(v.w);
    }
    float* rp = &red[grp][l15 * 8];
    rp[0]=a0; rp[1]=a1; rp[2]=a2; rp[3]=a3; rp[4]=a4; rp[5]=a5; rp[6]=a6; rp[7]=a7;
    __syncthreads();

    float acc = 0.f;
#pragma unroll
    for (int k = 0; k < 8; ++k) acc += red[k][t];
    float c = (e - s) > 0 ? (float)(e - s) : 1.0f;
    p[t] = acc / c;
    __syncthreads();

    float acc2 = b1[t];
#pragma unroll 8
    for (int k = 0; k < DIM; ++k) acc2 = fmaf(p[k], W1[k * DIM + t], acc2);
    float r = fmaxf(acc2, 0.f);
    float* rd = &red[0][0];
    rd[t] = r * W2[t];
    __syncthreads();
    for (int off = 64; off; off >>= 1) {
        if (t < off) rd[t] += rd[t + off];
        __syncthreads();
    }
    if (t == 0) out[g] = rd[0] + b2[0];
}

extern "C" void kernel_launch(void* const* d_in, const int* in_sizes, int n_in,
                              void* d_out, int out_size, void* d_ws, size_t ws_size,
                              hipStream_t stream) {
    (void)in_sizes; (void)n_in; (void)out_size; (void)ws_size;
    const float* x     = (const float*)d_in[0];
    const int*   ei    = (const int*)d_in[1];
    const int*   xb    = (const int*)d_in[3];
    const float* c0W1  = (const float*)d_in[4];
    const float* c0b1  = (const float*)d_in[5];
    const float* c0W2  = (const float*)d_in[6];
    const float* c0b2  = (const float*)d_in[7];
    const float* c1W1  = (const float*)d_in[8];
    const float* c1b1  = (const float*)d_in[9];
    const float* c1W2  = (const float*)d_in[10];
    const float* c1b2  = (const float*)d_in[11];
    const float* rW1   = (const float*)d_in[12];
    const float* rb1   = (const float*)d_in[13];
    const float* rW2   = (const float*)d_in[14];
    const float* rb2   = (const float*)d_in[15];
    float* out = (float*)d_out;

    char* ws = (char*)d_ws;
    size_t off = 0;
    auto alloc = [&](size_t bytes) -> char* {
        char* p = ws + off;
        off = (off + bytes + 511) & ~(size_t)511;
        return p;
    };
    int*    cnt    = (int*)alloc((size_t)N_NODES * 4);
    int*    cursor = (int*)alloc((size_t)N_NODES * 4);
    int*    rowptr = (int*)alloc((size_t)(N_NODES + 1) * 4);
    int*    csr    = (int*)alloc((size_t)N_EDGES * 4);
    ushort* xbf    = (ushort*)alloc((size_t)N_NODES * DIM * 2);
    ushort* aggbf  = (ushort*)alloc((size_t)N_NODES * DIM * 2);
    ushort* hbf    = (ushort*)alloc((size_t)N_NODES * DIM * 2);
    short*  Wp     = (short*)alloc((size_t)4 * DIM * DIM * 2);

    // cooperative setup: prep | count | rowptr | fill  (low-VGPR, no spill)
    void* args[] = { &x, &ei, &c0W1, &c0W2, &c1W1, &c1W2,
                     &xbf, &Wp, &cnt, &cursor, &rowptr, &csr };
    int nb = 0;
    hipOccupancyMaxActiveBlocksPerMultiprocessor(&nb, setup_kernel, 256, 0);
    if (nb < 1) nb = 1;
    int grid = nb * 256;
    if (grid > 1024) grid = 1024;
    hipLaunchCooperativeKernel(reinterpret_cast<void*>(setup_kernel),
                               dim3(grid), dim3(256), args, 0, stream);

    const int AB = (N_NODES * 16 + 255) / 256;   // 16 lanes per node
    const int MB = (N_NODES + 63) / 64;          // 64 nodes per block (2 waves)

    agg_kernel<<<AB, 256, 0, stream>>>(xbf, rowptr, csr, aggbf);
    mlp_kernel<<<MB, 128, 0, stream>>>(aggbf, Wp + 0 * 16384, c0b1, Wp + 1 * 16384, c0b2, hbf);
    agg_kernel<<<AB, 256, 0, stream>>>(hbf, rowptr, csr, aggbf);
    mlp_kernel<<<MB, 128, 0, stream>>>(aggbf, Wp + 2 * 16384, c1b1, Wp + 3 * 16384, c1b2, hbf);

    poolreg_kernel<<<N_GRAPHS, 128, 0, stream>>>(hbf, xb, rW1, rb1, rW2, rb2, out);
}

// Round 10
// 168.993 us; speedup vs baseline: 4.6410x; 3.1279x over previous
//
#include <hip/hip_runtime.h>
#include <stdint.h>

#define N_NODES 50000
#define N_EDGES 600000
#define DIM     128
#define N_GRAPHS 512
#define NB_SCAN 49            // ceil(50000/1024)

typedef __attribute__((ext_vector_type(8))) short bf16x8;
typedef __attribute__((ext_vector_type(4))) float f32x4;

__device__ __forceinline__ short f2bf(float f) {
    union { float f; uint32_t u; } c; c.f = f;
    uint32_t u = c.u;
    u += 0x7fffu + ((u >> 16) & 1u);   // round-to-nearest-even
    return (short)(u >> 16);
}
__device__ __forceinline__ float bflo(uint32_t u) {
    union { uint32_t u; float f; } c; c.u = u << 16; return c.f;
}
__device__ __forceinline__ float bfhi(uint32_t u) {
    union { uint32_t u; float f; } c; c.u = u & 0xffff0000u; return c.f;
}

#define N8_CVT (N_NODES * DIM / 8)        // 800000
#define NZ16   (N_NODES * 4 / 16)         // 12500 (cnt only; cursor set by rowptr_all)
#define NPACK  8192

// fused: x->bf16 cvt | zero cnt | pack 4 weight matrices
__global__ void prep_kernel(const float* __restrict__ x, ushort* __restrict__ xbf,
                            uint4* __restrict__ zeros16,
                            const float* __restrict__ W0, const float* __restrict__ W1,
                            const float* __restrict__ W2, const float* __restrict__ W3,
                            short* __restrict__ Wp) {
    int idx = blockIdx.x * blockDim.x + threadIdx.x;
    if (idx < N8_CVT) {
        const float4* p = (const float4*)(x + (size_t)idx * 8);
        float4 lo = p[0], hi = p[1];
        bf16x8 t;
        t[0] = f2bf(lo.x); t[1] = f2bf(lo.y); t[2] = f2bf(lo.z); t[3] = f2bf(lo.w);
        t[4] = f2bf(hi.x); t[5] = f2bf(hi.y); t[6] = f2bf(hi.z); t[7] = f2bf(hi.w);
        *(bf16x8*)(xbf + (size_t)idx * 8) = t;
        return;
    }
    int z = idx - N8_CVT;
    if (z < NZ16) { zeros16[z] = make_uint4(0, 0, 0, 0); return; }
    int pk = z - NZ16;
    if (pk < NPACK) {
        int m = pk >> 11;
        int r = pk & 2047;
        const float* W = (m == 0) ? W0 : (m == 1) ? W1 : (m == 2) ? W2 : W3;
        int lane = r & 63;
        int ks = (r >> 6) & 3;
        int nt = r >> 8;
        int col = nt * 16 + (lane & 15);
        int k0 = ks * 32 + ((lane >> 4) << 3);
        short* dst = Wp + (size_t)pk * 8;
#pragma unroll
        for (int j = 0; j < 8; ++j) dst[j] = f2bf(W[(k0 + j) * DIM + col]);
    }
}

__global__ void count_kernel(const int* __restrict__ ei, int* __restrict__ cnt) {
    int e = blockIdx.x * blockDim.x + threadIdx.x;
    if (e < N_EDGES) atomicAdd(&cnt[ei[N_EDGES + e]], 1);
}

// single kernel: per-block redundant prefix base + local scan -> rowptr, cursor
__global__ __launch_bounds__(1024) void rowptr_all_kernel(const int* __restrict__ cnt,
                                                          int* __restrict__ rowptr,
                                                          int* __restrict__ cursor) {
    __shared__ int s[1024];
    const int b = blockIdx.x, t = threadIdx.x;
    int partial = 0;
    const int lim = b << 10;
    for (int j = t; j < lim; j += 1024) partial += cnt[j];
    s[t] = partial;
    __syncthreads();
#pragma unroll
    for (int off = 512; off; off >>= 1) {
        if (t < off) s[t] += s[t + off];
        __syncthreads();
    }
    const int base = s[0];
    __syncthreads();
    int i = lim + t;
    int v = (i < N_NODES) ? cnt[i] : 0;
    s[t] = v;
    __syncthreads();
#pragma unroll
    for (int off = 1; off < 1024; off <<= 1) {
        int u = (t >= off) ? s[t - off] : 0;
        __syncthreads();
        s[t] += u;
        __syncthreads();
    }
    if (i < N_NODES) {
        rowptr[i + 1] = base + s[t];
        cursor[i] = base + s[t] - v;   // exclusive start = rowptr[i]
    }
    if (i == 0) rowptr[0] = 0;
}

__global__ void fill_kernel(const int* __restrict__ ei, int* __restrict__ cursor,
                            int* __restrict__ csr_src) {
    int e = blockIdx.x * blockDim.x + threadIdx.x;
    if (e < N_EDGES) {
        int dst = ei[N_EDGES + e];
        int p = atomicAdd(&cursor[dst], 1);
        csr_src[p] = ei[e];
    }
}

// one 16-lane group per node (16 lanes x 16B = full 256B row), 4 nodes/wave,
// edge loop 4/1-unrolled (proven round-5/7 config)
__global__ __launch_bounds__(256) void agg_kernel(const ushort* __restrict__ h,
                                                  const int* __restrict__ rowptr,
                                                  const int* __restrict__ csr_src,
                                                  ushort* __restrict__ agg) {
    int node = (blockIdx.x * 256 + threadIdx.x) >> 4;
    if (node >= N_NODES) return;
    int l15 = threadIdx.x & 15;
    const uint4* h4 = (const uint4*)h;

    uint4 v = h4[(size_t)node * 16 + l15];    // self-loop
    float a0 = bflo(v.x), a1 = bfhi(v.x), a2 = bflo(v.y), a3 = bfhi(v.y);
    float a4 = bflo(v.z), a5 = bfhi(v.z), a6 = bflo(v.w), a7 = bfhi(v.w);

    const int s = rowptr[node];
    const int e = rowptr[node + 1];
    int i = s;
    for (; i + 3 < e; i += 4) {
        int i0 = csr_src[i], i1 = csr_src[i + 1], i2 = csr_src[i + 2], i3 = csr_src[i + 3];
        uint4 v0 = h4[(size_t)i0 * 16 + l15];
        uint4 v1 = h4[(size_t)i1 * 16 + l15];
        uint4 v2 = h4[(size_t)i2 * 16 + l15];
        uint4 v3 = h4[(size_t)i3 * 16 + l15];
        a0 += bflo(v0.x); a1 += bfhi(v0.x); a2 += bflo(v0.y); a3 += bfhi(v0.y);
        a4 += bflo(v0.z); a5 += bfhi(v0.z); a6 += bflo(v0.w); a7 += bfhi(v0.w);
        a0 += bflo(v1.x); a1 += bfhi(v1.x); a2 += bflo(v1.y); a3 += bfhi(v1.y);
        a4 += bflo(v1.z); a5 += bfhi(v1.z); a6 += bflo(v1.w); a7 += bfhi(v1.w);
        a0 += bflo(v2.x); a1 += bfhi(v2.x); a2 += bflo(v2.y); a3 += bfhi(v2.y);
        a4 += bflo(v2.z); a5 += bfhi(v2.z); a6 += bflo(v2.w); a7 += bfhi(v2.w);
        a0 += bflo(v3.x); a1 += bfhi(v3.x); a2 += bflo(v3.y); a3 += bfhi(v3.y);
        a4 += bflo(v3.z); a5 += bfhi(v3.z); a6 += bflo(v3.w); a7 += bfhi(v3.w);
    }
    for (; i < e; ++i) {
        uint4 v0 = h4[(size_t)csr_src[i] * 16 + l15];
        a0 += bflo(v0.x); a1 += bfhi(v0.x); a2 += bflo(v0.y); a3 += bfhi(v0.y);
        a4 += bflo(v0.z); a5 += bfhi(v0.z); a6 += bflo(v0.w); a7 += bfhi(v0.w);
    }

    uint4 r;
    r.x = (uint32_t)(uint16_t)f2bf(a0) | ((uint32_t)(uint16_t)f2bf(a1) << 16);
    r.y = (uint32_t)(uint16_t)f2bf(a2) | ((uint32_t)(uint16_t)f2bf(a3) << 16);
    r.z = (uint32_t)(uint16_t)f2bf(a4) | ((uint32_t)(uint16_t)f2bf(a5) << 16);
    r.w = (uint32_t)(uint16_t)f2bf(a6) | ((uint32_t)(uint16_t)f2bf(a7) << 16);
    ((uint4*)agg)[(size_t)node * 16 + l15] = r;
}

// h_out = relu(A @ W1 + b1) @ W2 + b2 ; 32 nodes/wave, 2 waves/block (proven)
__global__ __launch_bounds__(128) void mlp_kernel(const ushort* __restrict__ A,
                                                  const short* __restrict__ W1p,
                                                  const float* __restrict__ b1,
                                                  const short* __restrict__ W2p,
                                                  const float* __restrict__ b2,
                                                  ushort* __restrict__ Hout) {
    __shared__ short tbuf[2][32 * 144];
    const int tid = threadIdx.x;
    const int wid = tid >> 6;              // 0..1
    const int lane = tid & 63;
    const int l15 = lane & 15;
    const int lg = lane >> 4;              // 0..3
    const int node0 = blockIdx.x * 64 + wid * 32;

    int rowA = node0 + l15;      if (rowA >= N_NODES) rowA = N_NODES - 1;
    int rowB = node0 + 16 + l15; if (rowB >= N_NODES) rowB = N_NODES - 1;
    const short* apA = (const short*)A + (size_t)rowA * DIM + lg * 8;
    const short* apB = (const short*)A + (size_t)rowB * DIM + lg * 8;
    bf16x8 afrA[4], afrB[4];
#pragma unroll
    for (int ks = 0; ks < 4; ++ks) {
        afrA[ks] = *(const bf16x8*)(apA + ks * 32);
        afrB[ks] = *(const bf16x8*)(apB + ks * 32);
    }

    short* tb = tbuf[wid];
#pragma unroll
    for (int nt = 0; nt < 8; ++nt) {
        f32x4 accA = {0.f, 0.f, 0.f, 0.f};
        f32x4 accB = {0.f, 0.f, 0.f, 0.f};
#pragma unroll
        for (int ks = 0; ks < 4; ++ks) {
            bf16x8 b = *(const bf16x8*)(W1p + (size_t)(((nt * 4 + ks) << 6) + lane) * 8);
            accA = __builtin_amdgcn_mfma_f32_16x16x32_bf16(afrA[ks], b, accA, 0, 0, 0);
            accB = __builtin_amdgcn_mfma_f32_16x16x32_bf16(afrB[ks], b, accB, 0, 0, 0);
        }
        float bias = b1[nt * 16 + l15];
#pragma unroll
        for (int i = 0; i < 4; ++i) {
            int r = lg * 4 + i;
            tb[r * 144 + nt * 16 + l15] = f2bf(fmaxf(accA[i] + bias, 0.f));
            tb[(r + 16) * 144 + nt * 16 + l15] = f2bf(fmaxf(accB[i] + bias, 0.f));
        }
    }
    __syncthreads();

    bf16x8 a2A[4], a2B[4];
#pragma unroll
    for (int ks = 0; ks < 4; ++ks) {
        a2A[ks] = *(const bf16x8*)(tb + l15 * 144 + ks * 32 + lg * 8);
        a2B[ks] = *(const bf16x8*)(tb + (16 + l15) * 144 + ks * 32 + lg * 8);
    }
    __syncthreads();

#pragma unroll
    for (int nt = 0; nt < 8; ++nt) {
        f32x4 accA = {0.f, 0.f, 0.f, 0.f};
        f32x4 accB = {0.f, 0.f, 0.f, 0.f};
#pragma unroll
        for (int ks = 0; ks < 4; ++ks) {
            bf16x8 b = *(const bf16x8*)(W2p + (size_t)(((nt * 4 + ks) << 6) + lane) * 8);
            accA = __builtin_amdgcn_mfma_f32_16x16x32_bf16(a2A[ks], b, accA, 0, 0, 0);
            accB = __builtin_amdgcn_mfma_f32_16x16x32_bf16(a2B[ks], b, accB, 0, 0, 0);
        }
        float bias = b2[nt * 16 + l15];
#pragma unroll
        for (int i = 0; i < 4; ++i) {
            int r = lg * 4 + i;
            tb[r * 144 + nt * 16 + l15] = f2bf(accA[i] + bias);
            tb[(r + 16) * 144 + nt * 16 + l15] = f2bf(accB[i] + bias);
        }
    }
    __syncthreads();

#pragma unroll
    for (int it = 0; it < 8; ++it) {
        int chunk = it * 64 + lane;    // 0..511
        int row = chunk >> 4;          // 0..31
        int seg = chunk & 15;
        bf16x8 v = *(const bf16x8*)(tb + row * 144 + seg * 8);
        int node = node0 + row;
        if (node < N_NODES) *(bf16x8*)((short*)Hout + (size_t)node * DIM + seg * 8) = v;
    }
}

// fused mean-pool + regressor MLP: one block (128 threads) per graph
__global__ __launch_bounds__(128) void poolreg_kernel(const ushort* __restrict__ h,
                                                      const int* __restrict__ xb,
                                                      const float* __restrict__ W1,
                                                      const float* __restrict__ b1,
                                                      const float* __restrict__ W2,
                                                      const float* __restrict__ b2,
                                                      float* __restrict__ out) {
    __shared__ float red[8][128];
    __shared__ float p[128];
    int g = blockIdx.x;
    int t = threadIdx.x;
    int grp = t >> 4;     // 0..7
    int l15 = t & 15;

    int lo = 0, hi = N_NODES;
    while (lo < hi) { int m = (lo + hi) >> 1; if (xb[m] < g) lo = m + 1; else hi = m; }
    int s = lo;
    hi = N_NODES;
    while (lo < hi) { int m = (lo + hi) >> 1; if (xb[m] < g + 1) lo = m + 1; else hi = m; }
    int e = lo;

    const uint4* h4 = (const uint4*)h;
    float a0=0,a1=0,a2=0,a3=0,a4=0,a5=0,a6=0,a7=0;
    for (int i = s + grp; i < e; i += 8) {
        uint4 v = h4[(size_t)i * 16 + l15];
        a0 += bflo(v.x); a1 += bfhi(v.x); a2 += bflo(v.y); a3 += bfhi(v.y);
        a4 += bflo(v.z); a5 += bfhi(v.z); a6 += bflo(v.w); a7 += bfhi(v.w);
    }
    float* rp = &red[grp][l15 * 8];
    rp[0]=a0; rp[1]=a1; rp[2]=a2; rp[3]=a3; rp[4]=a4; rp[5]=a5; rp[6]=a6; rp[7]=a7;
    __syncthreads();

    float acc = 0.f;
#pragma unroll
    for (int k = 0; k < 8; ++k) acc += red[k][t];
    float c = (e - s) > 0 ? (float)(e - s) : 1.0f;
    p[t] = acc / c;
    __syncthreads();

    float acc2 = b1[t];
#pragma unroll 8
    for (int k = 0; k < DIM; ++k) acc2 = fmaf(p[k], W1[k * DIM + t], acc2);
    float r = fmaxf(acc2, 0.f);
    float* rd = &red[0][0];
    rd[t] = r * W2[t];
    __syncthreads();
    for (int off = 64; off; off >>= 1) {
        if (t < off) rd[t] += rd[t + off];
        __syncthreads();
    }
    if (t == 0) out[g] = rd[0] + b2[0];
}

extern "C" void kernel_launch(void* const* d_in, const int* in_sizes, int n_in,
                              void* d_out, int out_size, void* d_ws, size_t ws_size,
                              hipStream_t stream) {
    (void)in_sizes; (void)n_in; (void)out_size; (void)ws_size;
    const float* x     = (const float*)d_in[0];
    const int*   ei    = (const int*)d_in[1];
    const int*   xb    = (const int*)d_in[3];
    const float* c0W1  = (const float*)d_in[4];
    const float* c0b1  = (const float*)d_in[5];
    const float* c0W2  = (const float*)d_in[6];
    const float* c0b2  = (const float*)d_in[7];
    const float* c1W1  = (const float*)d_in[8];
    const float* c1b1  = (const float*)d_in[9];
    const float* c1W2  = (const float*)d_in[10];
    const float* c1b2  = (const float*)d_in[11];
    const float* rW1   = (const float*)d_in[12];
    const float* rb1   = (const float*)d_in[13];
    const float* rW2   = (const float*)d_in[14];
    const float* rb2   = (const float*)d_in[15];
    float* out = (float*)d_out;

    char* ws = (char*)d_ws;
    size_t off = 0;
    auto alloc = [&](size_t bytes) -> char* {
        char* p = ws + off;
        off = (off + bytes + 511) & ~(size_t)511;
        return p;
    };
    int*    cnt    = (int*)alloc((size_t)N_NODES * 4);
    int*    cursor = (int*)alloc((size_t)N_NODES * 4);
    int*    rowptr = (int*)alloc((size_t)(N_NODES + 1) * 4);
    int*    csr    = (int*)alloc((size_t)N_EDGES * 4);
    ushort* xbf    = (ushort*)alloc((size_t)N_NODES * DIM * 2);
    ushort* aggbf  = (ushort*)alloc((size_t)N_NODES * DIM * 2);
    ushort* hbf    = (ushort*)alloc((size_t)N_NODES * DIM * 2);
    short*  Wp     = (short*)alloc((size_t)4 * DIM * DIM * 2);

    // fused prep: cvt x -> bf16 | zero cnt | pack weights
    const int PREP_TOTAL = N8_CVT + NZ16 + NPACK;
    prep_kernel<<<(PREP_TOTAL + 255) / 256, 256, 0, stream>>>(
        x, xbf, (uint4*)cnt, c0W1, c0W2, c1W1, c1W2, Wp);

    const int EB = (N_EDGES + 255) / 256;
    count_kernel<<<EB, 256, 0, stream>>>(ei, cnt);
    rowptr_all_kernel<<<NB_SCAN, 1024, 0, stream>>>(cnt, rowptr, cursor);
    fill_kernel<<<EB, 256, 0, stream>>>(ei, cursor, csr);

    const int AB = (N_NODES * 16 + 255) / 256;   // 16 lanes per node
    const int MB = (N_NODES + 63) / 64;          // 64 nodes per block (2 waves)

    agg_kernel<<<AB, 256, 0, stream>>>(xbf, rowptr, csr, aggbf);
    mlp_kernel<<<MB, 128, 0, stream>>>(aggbf, Wp + 0 * 16384, c0b1, Wp + 1 * 16384, c0b2, hbf);
    agg_kernel<<<AB, 256, 0, stream>>>(hbf, rowptr, csr, aggbf);
    mlp_kernel<<<MB, 128, 0, stream>>>(aggbf, Wp + 2 * 16384, c1b1, Wp + 3 * 16384, c1b2, hbf);

    poolreg_kernel<<<N_GRAPHS, 128, 0, stream>>>(hbf, xb, rW1, rb1, rW2, rb2, out);
}